// Round 6
// baseline (188.248 us; speedup 1.0000x reference)
//
#include <hip/hip_runtime.h>
#include <math.h>

#define Bb 4
#define Hh 128
#define Ww 256
#define Cc 64
#define Ff 128
#define INH 130   // H+2
#define INW 258   // W+2

#define WSLOT 72   // shorts per column (64 + 8 pad): 144B stride, 16B-aligned
#define WCOLS 132  // cols 0..130 = data window, col 131 = dedicated zero column

typedef __attribute__((ext_vector_type(8))) __bf16 bf16x8;
typedef __attribute__((ext_vector_type(4))) __bf16 bf16x4;
typedef __attribute__((ext_vector_type(4))) float floatx4;

// ---------------------------------------------------------------------------
// Prep: pack conv kernel [576][128] f32 into MFMA-B-frag order, bf16.
// chunk = ((tap*2+kk)*2+nh)*4+ni ; value(chunk,lane,s) =
//   kmat[(tap*64+kk*32+(lane>>4)*8+s)*128 + nh*64+ni*16+(lane&15)]
// B-frag read in fused kernel = 1KB contiguous per wave, L2-resident.
// (r3/r4 A/B: global B adds ~nothing to FETCH — the r3 explosion was the fill.)
// ---------------------------------------------------------------------------
__global__ void prep_kernel(const float* __restrict__ kmat,
                            unsigned short* __restrict__ kTp) {
  int gid = blockIdx.x * 256 + threadIdx.x;
  int lane = gid & 63;
  int chunk = gid >> 6;
  if (chunk >= 144) return;
  int ni  = chunk & 3;
  int nh  = (chunk >> 2) & 1;
  int kk  = (chunk >> 3) & 1;
  int tap = chunk >> 4;
  int n  = nh * 64 + ni * 16 + (lane & 15);
  int k0 = tap * 64 + kk * 32 + (lane >> 4) * 8;
  bf16x8 v;
#pragma unroll
  for (int s = 0; s < 8; s++) v[s] = (__bf16)kmat[(k0 + s) * 128 + n];
  *(bf16x8*)(kTp + chunk * 512 + lane * 8) = v;
}

// ---------------------------------------------------------------------------
// Fused, software-pipelined over taps:
//   prologue: fill(0) -> regs
//   per tap: store regs -> winH[tap&1]; ONE __syncthreads; issue fill(tap+1)
//            (global loads in flight under the MFMA below, premix consumes
//            them before the next barrier -> no vmcnt drain at barrier);
//            MFMA from winH[tap&1] + B-frags from global kTp.
// Double-buffered winH makes the single barrier sufficient:
//   R(buf,t-1) < bar_t < W(buf,t+1).
// ---------------------------------------------------------------------------
__global__ __launch_bounds__(256, 3) void fused_kernel(
    const float* __restrict__ in, const float* __restrict__ bias,
    const unsigned short* __restrict__ kTp, const float* __restrict__ offtab,
    float* __restrict__ out) {
  __shared__ unsigned short winH[2][WCOLS * WSLOT];

  // XCD swizzle: each XCD gets one b and a contiguous h-range (~4.4MB == L2)
  int lidx = ((blockIdx.x & 7) << 7) | (blockIdx.x >> 3);
  int wt = lidx & 1;
  int h  = (lidx >> 1) & 127;
  int b  = lidx >> 8;
  int w0 = wt << 7;

  int tid  = threadIdx.x;
  int lane = tid & 63;
  int wave = tid >> 6;
  int m_base = (wave >> 1) << 6;
  int nh     = wave & 1;          // which 64-wide F half
  int l15  = lane & 15;
  int quad = lane >> 4;

  floatx4 acc[4][4];
#pragma unroll
  for (int i = 0; i < 4; i++)
#pragma unroll
    for (int j = 0; j < 4; j++) acc[i][j] = (floatx4){0.f, 0.f, 0.f, 0.f};

  const float* inb = in + (size_t)b * Hh * Ww * Cc;

  bf16x4 frg[2][3][4];   // premixed fill data, parity-indexed
  int    sl[2][4];       // per-lane A-slot per m-frag, parity-indexed

  auto do_fill = [&](int tap, int pb) {
    float off0 = offtab[(h * 9 + tap) * 2 + 0];
    float off1 = offtab[(h * 9 + tap) * 2 + 1];
    float dyk = (float)(tap / 3), dxk = (float)(tap % 3);

    // y side (block-uniform): rows + weights, pad folded into weights
    float y = (float)h + dyk + off0;
    y = fminf(fmaxf(y, 0.f), (float)(INH - 1));
    int y0i = (int)floorf(y);
    int y1i = y0i + 1;
    y0i = min(max(y0i, 0), INH - 1);
    y1i = min(max(y1i, 0), INH - 1);
    float wy0 = (float)y1i - y;
    float wy1 = y - (float)y0i;
    if (!(y0i >= 1 && y0i <= Hh)) wy0 = 0.f;
    if (!(y1i >= 1 && y1i <= Hh)) wy1 = 0.f;
    const float* row0 = inb + (size_t)min(max(y0i - 1, 0), Hh - 1) * Ww * Cc;
    const float* row1 = inb + (size_t)min(max(y1i - 1, 0), Hh - 1) * Ww * Cc;

    // x side: block-uniform fractional weights + window base
    float xrep = (float)w0 + dxk + off1;
    float flo  = floorf(xrep);
    int jb = (int)flo - 1;
    float fx = xrep - flo;
    float q00 = wy0 * (1.f - fx), q01 = wy0 * fx;
    float q10 = wy1 * (1.f - fx), q11 = wy1 * fx;

    // per-lane slots (faithful ref op order)
#pragma unroll
    for (int mi = 0; mi < 4; mi++) {
      int w = m_base + mi * 16 + l15;
      float x = (float)(w0 + w) + dxk + off1;
      if (x < 0.f) x += (float)INW;
      if (x > (float)(INW - 1)) x -= (float)INW;
      int x0i = (int)floorf(x);
      int s = x0i - jb;
      if (s < 0) s += INW;
      if (s > 131) s = 131;
      sl[pb][mi] = s;
    }

    // 132 cols x 4 lane-chunks = 528 tasks; sector-aligned; tail clamped
    // (threads on task 527 redundantly recompute the zero column: no branch)
#pragma unroll
    for (int it = 0; it < 3; it++) {
      int task = min(tid + (it << 8), 527);
      int j   = task >> 2;
      int c4f = (task & 3) << 2;
      int col = jb + j;
      if (col < 0) col += INW;
      if (col > INW - 1) col -= INW;
      int ncol = jb + j + 1;
      if (ncol < 0) ncol += INW;
      if (ncol > INW - 1) ncol -= INW;
      bool cok = (col >= 1) & (col <= Ww) & (j < 131);
      bool nok = (ncol >= 1) & (ncol <= Ww) & (j < 131);
      int ci = min(max(col - 1, 0), Ww - 1);
      int nx = min(max(ncol - 1, 0), Ww - 1);
      float w00 = cok ? q00 : 0.f, w01 = nok ? q01 : 0.f;
      float w10 = cok ? q10 : 0.f, w11 = nok ? q11 : 0.f;
      const float* p0 = row0 + ci * Cc + c4f;
      const float* p1 = row0 + nx * Cc + c4f;
      const float* p2 = row1 + ci * Cc + c4f;
      const float* p3 = row1 + nx * Cc + c4f;
#pragma unroll
      for (int q = 0; q < 4; q++) {
        // channels q*16 + c4f + 0..3 ; lanes of a quad read 64B contiguous
        float4 a0 = *(const float4*)(p0 + q * 16);
        float4 a1 = *(const float4*)(p1 + q * 16);
        float4 b0 = *(const float4*)(p2 + q * 16);
        float4 b1 = *(const float4*)(p3 + q * 16);
        float px = w00 * a0.x + w01 * a1.x + w10 * b0.x + w11 * b1.x;
        float py = w00 * a0.y + w01 * a1.y + w10 * b0.y + w11 * b1.y;
        float pz = w00 * a0.z + w01 * a1.z + w10 * b0.z + w11 * b1.z;
        float pw = w00 * a0.w + w01 * a1.w + w10 * b0.w + w11 * b1.w;
        bf16x4 o;
        o[0] = (__bf16)px; o[1] = (__bf16)py;
        o[2] = (__bf16)pz; o[3] = (__bf16)pw;
        frg[pb][it][q] = o;
      }
    }
  };

  do_fill(0, 0);

#pragma unroll
  for (int tap = 0; tap < 9; tap++) {
    int buf = tap & 1;

    // store premixed tap data -> winH[buf]
#pragma unroll
    for (int it = 0; it < 3; it++) {
      int task = min(tid + (it << 8), 527);
      int j   = task >> 2;
      int c4f = (task & 3) << 2;
#pragma unroll
      for (int q = 0; q < 4; q++)
        *(bf16x4*)&winH[buf][j * WSLOT + q * 16 + c4f] = frg[buf][it][q];
    }

    __syncthreads();

    // prefetch next tap (global loads fly under the MFMA below)
    if (tap < 8) do_fill(tap + 1, buf ^ 1);

    // MFMA: A-frags from winH[buf], B-frags from pre-packed global kTp
#pragma unroll
    for (int kk = 0; kk < 2; kk++) {
      bf16x8 afrag[4], bfrag[4];
      const unsigned short* kb =
          kTp + (size_t)((((tap * 2 + kk) * 2 + nh) * 4) * 512) + lane * 8;
#pragma unroll
      for (int ni = 0; ni < 4; ni++)
        bfrag[ni] = *(const bf16x8*)(kb + ni * 512);
#pragma unroll
      for (int mi = 0; mi < 4; mi++)
        afrag[mi] = *(const bf16x8*)&winH[buf][sl[buf][mi] * WSLOT + kk * 32 + quad * 8];
#pragma unroll
      for (int mi = 0; mi < 4; mi++)
#pragma unroll
        for (int ni = 0; ni < 4; ni++)
          acc[mi][ni] = __builtin_amdgcn_mfma_f32_16x16x32_bf16(
              afrag[mi], bfrag[ni], acc[mi][ni], 0, 0, 0);
    }
    // single barrier per tap: R(buf,t-1) < bar_t < W(buf,t+1) keeps dbuf safe
  }

  // ---- epilogue: bias + relu (C/D: col=lane&15, row=quad*4+r) ----
  size_t outbase = ((size_t)(b * Hh + h) * Ww + w0);
#pragma unroll
  for (int ni = 0; ni < 4; ni++) {
    int f = nh * 64 + ni * 16 + l15;
    float bv = bias[f];
#pragma unroll
    for (int mi = 0; mi < 4; mi++) {
#pragma unroll
      for (int r = 0; r < 4; r++) {
        int m = m_base + mi * 16 + quad * 4 + r;
        out[(outbase + m) * Ff + f] = fmaxf(acc[mi][ni][r] + bv, 0.f);
      }
    }
  }
}

// ---------------------------------------------------------------------------
// Host-side fp64 offset table (faithful numpy port; fp64 required: fp32 flips
// the ux>0 branch at h=0 where cos(pi/2)~6e-17 -> half-width x shift).
// ---------------------------------------------------------------------------
static float h_off[Hh * 9 * 2];

static void compute_offsets_host() {
  const double pi = 3.14159265358979323846;
  double unit_w = 2.0 * pi / (double)Ww;
  double unit_h = pi / (2.0 * (double)Hh);
  double rho = tan(unit_w);
  double theta = ((double)(Ww / 2) - 0.5 * (double)Ww) * unit_w;
  static const int r0t[9] = {1, 1, 1, 0, 0, 0, -1, -1, -1};
  static const int r1t[9] = {-1, 0, 1, -1, 0, 1, -1, 0, 1};
  for (int h = 0; h < Hh; h++) {
    double phi = ((double)Hh - (double)h) * unit_h;
    double cph = cos(phi), sph = sin(phi);
    double cth = cos(theta), sth = sin(theta);
    double pux = cph * cth, puy = sph, puz = cph * sth;
    double txx = puz, txy = 0.0, txz = -pux;
    double tyx = puy * txz - puz * txy;
    double tyy = puz * txx - pux * txz;
    double tyz = pux * txy - puy * txx;
    double xr[10], yr[10];
    for (int p = 0; p < 10; p++) {
      int r0 = (p == 9) ? 0 : r0t[p];
      int r1 = (p == 9) ? 0 : r1t[p];
      double ux = pux + rho * ((double)r0 * txx + (double)r1 * tyx);
      double uy = puy + rho * ((double)r0 * txy + (double)r1 * tyy);
      double uz = puz + rho * ((double)r0 * txz + (double)r1 * tyz);
      double base = atan2(uz, ux);
      double th;
      if (ux > 0.0)        th = base;
      else if (ux < 0.0)   th = (uz >= 0.0) ? base + pi : base - pi;
      else                 th = (uz > 0.0) ? pi * 0.5 : -pi * 0.5;
      double ph = asin(uy);
      xr[p] = (th / pi + 1.0) * 0.5 * (double)Ww;
      yr[p] = (1.0 - 2.0 * ph / pi) * (double)Hh;
    }
    for (int j = 0; j < 9; j++) {
      h_off[(h * 9 + j) * 2 + 0] = (float)(xr[j] - xr[9]);  // added to y (faithful swap)
      h_off[(h * 9 + j) * 2 + 1] = (float)(yr[j] - yr[9]);  // added to x
    }
  }
}

extern "C" void kernel_launch(void* const* d_in, const int* in_sizes, int n_in,
                              void* d_out, int out_size, void* d_ws, size_t ws_size,
                              hipStream_t stream) {
  const float* in   = (const float*)d_in[0];
  const float* kmat = (const float*)d_in[1];
  const float* bias = (const float*)d_in[2];
  float* out = (float*)d_out;

  // ws layout: offtab (9216 B) | kTp (144 chunks x 1KB = 147456 B)
  float* offtab = (float*)d_ws;
  unsigned short* kTp = (unsigned short*)((char*)d_ws + Hh * 9 * 2 * sizeof(float));
  if (ws_size < (size_t)(Hh * 9 * 2 * sizeof(float) + 144 * 512 * sizeof(unsigned short)))
    return;

  compute_offsets_host();
  hipMemcpyAsync(offtab, h_off, sizeof(h_off), hipMemcpyHostToDevice, stream);
  prep_kernel<<<36, 256, 0, stream>>>(kmat, kTp);
  fused_kernel<<<Bb * Hh * (Ww / 128), 256, 0, stream>>>(in, bias, kTp, offtab, out);
}

// Round 7
// 176.403 us; speedup vs baseline: 1.0671x; 1.0671x over previous
//
#include <hip/hip_runtime.h>
#include <math.h>

#define Bb 4
#define Hh 128
#define Ww 256
#define Cc 64
#define Ff 128
#define INH 130   // H+2
#define INW 258   // W+2

#define WSLOT 72  // shorts per column (64 + 8 pad): 144B stride, 16B-aligned
#define WCOLS 69  // cols 0..67 = data window (64-w tile), col 68 = zero column

typedef __attribute__((ext_vector_type(8))) __bf16 bf16x8;
typedef __attribute__((ext_vector_type(4))) __bf16 bf16x4;
typedef __attribute__((ext_vector_type(4))) float floatx4;

// ---------------------------------------------------------------------------
// Prep: pack conv kernel [576][128] f32 into MFMA-B-frag order, bf16.
// chunk = (tap*2+kk)*8 + ni8  (ni8 = nh*4+ni); value(chunk,lane,s) =
//   kmat[(tap*64+kk*32+(lane>>4)*8+s)*128 + (ni8>>2)*64+(ni8&3)*16+(lane&15)]
// B-frag read in fused kernel = contiguous 1KB per wave, L2/L1-resident.
// ---------------------------------------------------------------------------
__global__ void prep_kernel(const float* __restrict__ kmat,
                            unsigned short* __restrict__ kTp) {
  int gid = blockIdx.x * 256 + threadIdx.x;
  int lane = gid & 63;
  int chunk = gid >> 6;
  if (chunk >= 144) return;
  int ni8 = chunk & 7;
  int kk  = (chunk >> 3) & 1;
  int tap = chunk >> 4;
  int n  = (ni8 >> 2) * 64 + (ni8 & 3) * 16 + (lane & 15);
  int k0 = tap * 64 + kk * 32 + (lane >> 4) * 8;
  bf16x8 v;
#pragma unroll
  for (int s = 0; s < 8; s++) v[s] = (__bf16)kmat[(k0 + s) * 128 + n];
  *(bf16x8*)(kTp + chunk * 512 + lane * 8) = v;
}

// ---------------------------------------------------------------------------
// Fused, BARRIER-FREE: one wave per block, one 64w x 128f tile per wave.
// Private 69-col premix window in LDS (double-buffered), zero __syncthreads:
// within-wave ds ordering is enforced by compiler lgkmcnt waits. 8 fully
// independent waves/CU give 8 latency streams (rounds 2-6 were serialized by
// per-tap block barriers with only 2-3 streams/CU).
// ---------------------------------------------------------------------------
__global__ __launch_bounds__(64, 2) void fused_kernel(
    const float* __restrict__ in, const float* __restrict__ bias,
    const unsigned short* __restrict__ kTp, const float* __restrict__ offtab,
    float* __restrict__ out) {
  __shared__ unsigned short winH[2][WCOLS * WSLOT];   // 2 x 9936 B

  // XCD swizzle: XCD k gets lidx k*256..k*256+255 = one b, contiguous h range
  // (~4.3MB input slice ~= one XCD L2)
  int lidx = ((blockIdx.x & 7) << 8) | (blockIdx.x >> 3);
  int wt = lidx & 3;
  int h  = (lidx >> 2) & 127;
  int b  = lidx >> 9;
  int w0 = wt << 6;

  int lane = threadIdx.x;     // 64 threads = 1 wave
  int l15  = lane & 15;
  int quad = lane >> 4;

  floatx4 acc[4][8];
#pragma unroll
  for (int i = 0; i < 4; i++)
#pragma unroll
    for (int j = 0; j < 8; j++) acc[i][j] = (floatx4){0.f, 0.f, 0.f, 0.f};

  const float* inb = in + (size_t)b * Hh * Ww * Cc;

  for (int tap = 0; tap < 9; tap++) {
    int buf = tap & 1;
    float off0 = offtab[(h * 9 + tap) * 2 + 0];
    float off1 = offtab[(h * 9 + tap) * 2 + 1];
    float dyk = (float)(tap / 3), dxk = (float)(tap % 3);

    // ---- y side (wave-uniform, SALU): rows + weights, pad -> weights ----
    float y = (float)h + dyk + off0;
    y = fminf(fmaxf(y, 0.f), (float)(INH - 1));
    int y0i = (int)floorf(y);
    int y1i = y0i + 1;
    y0i = min(max(y0i, 0), INH - 1);
    y1i = min(max(y1i, 0), INH - 1);
    float wy0 = (float)y1i - y;
    float wy1 = y - (float)y0i;
    if (!(y0i >= 1 && y0i <= Hh)) wy0 = 0.f;
    if (!(y1i >= 1 && y1i <= Hh)) wy1 = 0.f;
    const float* row0 = inb + (size_t)min(max(y0i - 1, 0), Hh - 1) * Ww * Cc;
    const float* row1 = inb + (size_t)min(max(y1i - 1, 0), Hh - 1) * Ww * Cc;

    // ---- x side: wave-uniform fractional weights + window base ----
    float xrep = (float)w0 + dxk + off1;
    float flo  = floorf(xrep);
    int jb = (int)flo - 1;
    float fx = xrep - flo;
    float q00 = wy0 * (1.f - fx), q01 = wy0 * fx;
    float q10 = wy1 * (1.f - fx), q11 = wy1 * fx;

    // ---- per-lane A slots (faithful ref op order); zero col = 68 ----
    int sl[4];
#pragma unroll
    for (int mi = 0; mi < 4; mi++) {
      int w = mi * 16 + l15;
      float x = (float)(w0 + w) + dxk + off1;
      if (x < 0.f) x += (float)INW;
      if (x > (float)(INW - 1)) x -= (float)INW;
      int x0i = (int)floorf(x);
      int s = x0i - jb;
      if (s < 0) s += INW;     // wrapped-high lanes land back in-window
      if (s > 68) s = 68;      // everything else -> zero column
      sl[mi] = s;
    }

    // ---- fill: 69 cols x 4 lane-chunks = 276 tasks over 5 its ----
    // sector-aligned: lanes (task&3) cover 64B contiguous per q-group.
    // mod-258 col ids make wrap premix correct; pad cols masked to zero.
#pragma unroll
    for (int it = 0; it < 5; it++) {
      int task = min(lane + (it << 6), 275);
      int j   = task >> 2;
      int c4f = (task & 3) << 2;
      int col = jb + j;
      if (col < 0) col += INW;
      if (col > INW - 1) col -= INW;
      int ncol = jb + j + 1;
      if (ncol < 0) ncol += INW;
      if (ncol > INW - 1) ncol -= INW;
      bool cok = (col >= 1) & (col <= Ww) & (j < 68);
      bool nok = (ncol >= 1) & (ncol <= Ww) & (j < 68);
      int ci = min(max(col - 1, 0), Ww - 1);
      int nx = min(max(ncol - 1, 0), Ww - 1);
      float w00 = cok ? q00 : 0.f, w01 = nok ? q01 : 0.f;
      float w10 = cok ? q10 : 0.f, w11 = nok ? q11 : 0.f;
      const float* p0 = row0 + ci * Cc + c4f;
      const float* p1 = row0 + nx * Cc + c4f;
      const float* p2 = row1 + ci * Cc + c4f;
      const float* p3 = row1 + nx * Cc + c4f;
#pragma unroll
      for (int q = 0; q < 4; q++) {
        float4 a0 = *(const float4*)(p0 + q * 16);
        float4 a1 = *(const float4*)(p1 + q * 16);
        float4 b0 = *(const float4*)(p2 + q * 16);
        float4 b1 = *(const float4*)(p3 + q * 16);
        float px = w00 * a0.x + w01 * a1.x + w10 * b0.x + w11 * b1.x;
        float py = w00 * a0.y + w01 * a1.y + w10 * b0.y + w11 * b1.y;
        float pz = w00 * a0.z + w01 * a1.z + w10 * b0.z + w11 * b1.z;
        float pw = w00 * a0.w + w01 * a1.w + w10 * b0.w + w11 * b1.w;
        bf16x4 o;
        o[0] = (__bf16)px; o[1] = (__bf16)py;
        o[2] = (__bf16)pz; o[3] = (__bf16)pw;
        *(bf16x4*)&winH[buf][j * WSLOT + q * 16 + c4f] = o;
      }
    }
    // no barrier: single wave; compiler inserts lgkmcnt before dependent reads

    // ---- MFMA: A from private window, B from pre-packed global kTp ----
#pragma unroll
    for (int kk = 0; kk < 2; kk++) {
      bf16x8 afrag[4], bfrag[8];
      const unsigned short* kb = kTp + (size_t)((tap * 2 + kk) * 8) * 512 + lane * 8;
#pragma unroll
      for (int ni = 0; ni < 8; ni++)
        bfrag[ni] = *(const bf16x8*)(kb + ni * 512);
#pragma unroll
      for (int mi = 0; mi < 4; mi++)
        afrag[mi] = *(const bf16x8*)&winH[buf][sl[mi] * WSLOT + kk * 32 + quad * 8];
#pragma unroll
      for (int mi = 0; mi < 4; mi++)
#pragma unroll
        for (int ni = 0; ni < 8; ni++)
          acc[mi][ni] = __builtin_amdgcn_mfma_f32_16x16x32_bf16(
              afrag[mi], bfrag[ni], acc[mi][ni], 0, 0, 0);
    }
  }

  // ---- epilogue: bias + relu (C/D: col=lane&15, row=quad*4+r) ----
  size_t outbase = ((size_t)(b * Hh + h) * Ww + w0);
#pragma unroll
  for (int ni = 0; ni < 8; ni++) {
    int f = (ni >> 2) * 64 + (ni & 3) * 16 + l15;
    float bv = bias[f];
#pragma unroll
    for (int mi = 0; mi < 4; mi++) {
#pragma unroll
      for (int r = 0; r < 4; r++) {
        int m = mi * 16 + quad * 4 + r;
        out[(outbase + m) * Ff + f] = fmaxf(acc[mi][ni][r] + bv, 0.f);
      }
    }
  }
}

// ---------------------------------------------------------------------------
// Host-side fp64 offset table (faithful numpy port; fp64 required: fp32 flips
// the ux>0 branch at h=0 where cos(pi/2)~6e-17 -> half-width x shift).
// ---------------------------------------------------------------------------
static float h_off[Hh * 9 * 2];

static void compute_offsets_host() {
  const double pi = 3.14159265358979323846;
  double unit_w = 2.0 * pi / (double)Ww;
  double unit_h = pi / (2.0 * (double)Hh);
  double rho = tan(unit_w);
  double theta = ((double)(Ww / 2) - 0.5 * (double)Ww) * unit_w;
  static const int r0t[9] = {1, 1, 1, 0, 0, 0, -1, -1, -1};
  static const int r1t[9] = {-1, 0, 1, -1, 0, 1, -1, 0, 1};
  for (int h = 0; h < Hh; h++) {
    double phi = ((double)Hh - (double)h) * unit_h;
    double cph = cos(phi), sph = sin(phi);
    double cth = cos(theta), sth = sin(theta);
    double pux = cph * cth, puy = sph, puz = cph * sth;
    double txx = puz, txy = 0.0, txz = -pux;
    double tyx = puy * txz - puz * txy;
    double tyy = puz * txx - pux * txz;
    double tyz = pux * txy - puy * txx;
    double xr[10], yr[10];
    for (int p = 0; p < 10; p++) {
      int r0 = (p == 9) ? 0 : r0t[p];
      int r1 = (p == 9) ? 0 : r1t[p];
      double ux = pux + rho * ((double)r0 * txx + (double)r1 * tyx);
      double uy = puy + rho * ((double)r0 * txy + (double)r1 * tyy);
      double uz = puz + rho * ((double)r0 * txz + (double)r1 * tyz);
      double base = atan2(uz, ux);
      double th;
      if (ux > 0.0)        th = base;
      else if (ux < 0.0)   th = (uz >= 0.0) ? base + pi : base - pi;
      else                 th = (uz > 0.0) ? pi * 0.5 : -pi * 0.5;
      double ph = asin(uy);
      xr[p] = (th / pi + 1.0) * 0.5 * (double)Ww;
      yr[p] = (1.0 - 2.0 * ph / pi) * (double)Hh;
    }
    for (int j = 0; j < 9; j++) {
      h_off[(h * 9 + j) * 2 + 0] = (float)(xr[j] - xr[9]);  // added to y (faithful swap)
      h_off[(h * 9 + j) * 2 + 1] = (float)(yr[j] - yr[9]);  // added to x
    }
  }
}

extern "C" void kernel_launch(void* const* d_in, const int* in_sizes, int n_in,
                              void* d_out, int out_size, void* d_ws, size_t ws_size,
                              hipStream_t stream) {
  const float* in   = (const float*)d_in[0];
  const float* kmat = (const float*)d_in[1];
  const float* bias = (const float*)d_in[2];
  float* out = (float*)d_out;

  // ws layout: offtab (9216 B) | kTp (144 chunks x 1KB = 147456 B)
  float* offtab = (float*)d_ws;
  unsigned short* kTp = (unsigned short*)((char*)d_ws + Hh * 9 * 2 * sizeof(float));
  if (ws_size < (size_t)(Hh * 9 * 2 * sizeof(float) + 144 * 512 * sizeof(unsigned short)))
    return;

  compute_offsets_host();
  hipMemcpyAsync(offtab, h_off, sizeof(h_off), hipMemcpyHostToDevice, stream);
  prep_kernel<<<36, 256, 0, stream>>>(kmat, kTp);
  fused_kernel<<<Bb * Hh * (Ww / 64), 64, 0, stream>>>(in, bias, kTp, offtab, out);
}